// Round 7
// baseline (200.813 us; speedup 1.0000x reference)
//
#include <hip/hip_runtime.h>
#include <hip/hip_bf16.h>

#define IN_F   1024
#define OUT_F  1024
#define TOKENS 8192
#define KTOT   9216
#define KHALF  4608
#define NTILE  72          // KHALF / 64

typedef __attribute__((ext_vector_type(8))) short  bf16x8;
typedef __attribute__((ext_vector_type(4))) float  f32x4;

template<int M> struct ModeT { static constexpr int value = M; };

__device__ __forceinline__ unsigned int f2bf(float f) {
    union { float f; unsigned int u; } v; v.f = f;
    unsigned int r = v.u + 0x7fffu + ((v.u >> 16) & 1u);
    return r >> 16;
}

__device__ __forceinline__ void prep_a_body(int idx, const float* __restrict__ x,
                                            const float* __restrict__ grid,
                                            unsigned short* __restrict__ A)
{
    int t = idx >> 10;
    int i = idx & 1023;
    float xv = x[idx];
    float sil = xv / (1.0f + __expf(-xv));
    A[(size_t)t * KTOT + i] = (unsigned short)f2bf(sil);

    const float invd = 1.0f / (2.0f / 7.0f + 1e-5f);
    unsigned int h[8];
    #pragma unroll
    for (int g = 0; g < 8; ++g) {
        float d = (xv - grid[g]) * invd;
        h[g] = f2bf(__expf(-d * d));
    }
    uint4 pk;
    pk.x = h[0] | (h[1] << 16);
    pk.y = h[2] | (h[3] << 16);
    pk.z = h[4] | (h[5] << 16);
    pk.w = h[6] | (h[7] << 16);
    *reinterpret_cast<uint4*>(&A[(size_t)t * KTOT + IN_F + (size_t)i * 8]) = pk;
}

__device__ __forceinline__ void prep_b_body(int idx, const float* __restrict__ W,
                                            const float* __restrict__ spl,
                                            unsigned short* __restrict__ B)
{
    int o  = idx / (KTOT / 8);
    int c8 = idx - o * (KTOT / 8);
    const float* src = (c8 < IN_F / 8)
        ? (W   + (size_t)o * IN_F     + (size_t)c8 * 8)
        : (spl + (size_t)o * IN_F * 8 + (size_t)(c8 - IN_F / 8) * 8);
    const float4* s4 = reinterpret_cast<const float4*>(src);
    float4 lo = s4[0], hi = s4[1];
    uint4 pk;
    pk.x = f2bf(lo.x) | (f2bf(lo.y) << 16);
    pk.y = f2bf(lo.z) | (f2bf(lo.w) << 16);
    pk.z = f2bf(hi.x) | (f2bf(hi.y) << 16);
    pk.w = f2bf(hi.z) | (f2bf(hi.w) << 16);
    *reinterpret_cast<uint4*>(&B[(size_t)o * KTOT + (size_t)c8 * 8]) = pk;
}

// Fused A+B prep: blocks [0, 32768) build A (silu + basis), rest repack B.
__global__ __launch_bounds__(256)
void prep_fused(const float* __restrict__ x, const float* __restrict__ grid,
                const float* __restrict__ W, const float* __restrict__ spl,
                unsigned short* __restrict__ A, unsigned short* __restrict__ B)
{
    int b = blockIdx.x;
    if (b < (TOKENS * IN_F) / 256)
        prep_a_body(b * 256 + threadIdx.x, x, grid, A);
    else
        prep_b_body((b - (TOKENS * IN_F) / 256) * 256 + threadIdx.x, W, spl, B);
}

__global__ __launch_bounds__(256)
void prep_a_kernel(const float* __restrict__ x, const float* __restrict__ grid,
                   unsigned short* __restrict__ A)
{
    prep_a_body(blockIdx.x * blockDim.x + threadIdx.x, x, grid, A);
}

__global__ __launch_bounds__(256)
void prep_b_kernel(const float* __restrict__ W, const float* __restrict__ spl,
                   unsigned short* __restrict__ B)
{
    prep_b_body(blockIdx.x * blockDim.x + threadIdx.x, W, spl, B);
}

// ---------------------------------------------------------------------------
// 256x256 tile, BK=64, 8 waves (2M x 4N), split-K=2.
// Barrier-minimal tile (R6) + T19 sched_group_barrier interleave:
// ~2 MFMA : 1 ds_read pinned so reads issue in the MFMA issue-stall gaps
// of the same wave (in-order waves can't otherwise overlap the two pipes).
//   A row(mi) = wr*64 + (mi&3)*16 + (mi>>2)*128
//   B col(ni) = wc*32 + (ni&1)*16 + (ni>>1)*128
// Body order: [af-lo,bfLo reads] q00 [bfHi reads] q01 [af-hi reads]
//             [gloads u+1] q10 q11 | SGB pin | vmcnt(0) barrier.
// ---------------------------------------------------------------------------
#define GLOAD(src, dst) __builtin_amdgcn_global_load_lds( \
    (const __attribute__((address_space(1))) void*)(src),  \
    (__attribute__((address_space(3))) void*)(dst), 16, 0, 0)
#define SBAR()  __builtin_amdgcn_s_barrier()
#define SCH0()  __builtin_amdgcn_sched_barrier(0)
#define VMC0()  asm volatile("s_waitcnt vmcnt(0)" ::: "memory")
#define SGB(m, n) __builtin_amdgcn_sched_group_barrier((m), (n), 0)
// masks: MFMA=0x8, VMEM|VMEM_READ=0x30, DS_READ=0x100

__global__ __launch_bounds__(512, 2)
void gemm_kan2(const unsigned short* __restrict__ A,
               const unsigned short* __restrict__ B,
               float* __restrict__ P, int rows)
{
    __shared__ char lds[131072];   // A dbuf [0,64K), B dbuf [64K,128K)

    const int bid  = blockIdx.x;
    const int sk   = bid & 1;            // XCD = bid&7 owns one (bn,sk) pair:
    const int bn   = (bid >> 1) & 3;     // its 2.36 MB B-panel stays in its L2
    const int bm   = bid >> 3;
    const int tid  = threadIdx.x;
    const int wave = tid >> 6, lane = tid & 63;
    const int wr   = wave >> 2, wc = wave & 3;
    const int fr   = lane & 15, kg = lane >> 4;
    const int sw   = fr & 7;
    const int koff[2] = { (kg ^ sw) * 16, ((4 | kg) ^ sw) * 16 };
    const int k0 = sk * KHALF;

    // staging: thread covers row (tid>>3), 16B chunk (tid&7), inverse-swizzled k
    const int trow = tid >> 3;
    const int ksrc = ((tid & 7) ^ (trow & 7)) * 8;
    const unsigned short* gA = A + (size_t)(bm * 256 + trow) * KTOT + k0 + ksrc;
    const unsigned short* gB = B + (size_t)(bn * 256 + trow) * KTOT + k0 + ksrc;
    const size_t R64 = (size_t)64 * KTOT;

    f32x4 acc[8][4];
    const f32x4 zero = {0.f, 0.f, 0.f, 0.f};
    #pragma unroll
    for (int m = 0; m < 8; ++m)
        #pragma unroll
        for (int n = 0; n < 4; ++n) acc[m][n] = zero;

    // prologue: stage tile 0 -> buf0
    {
        char* dA = lds + tid * 16;
        char* dB = lds + 65536 + tid * 16;
        GLOAD(gA,           dA);           GLOAD(gA + R64,     dA + 8192);
        GLOAD(gA + 2 * R64, dA + 16384);   GLOAD(gA + 3 * R64, dA + 24576);
        GLOAD(gB,           dB);           GLOAD(gB + R64,     dB + 8192);
        GLOAD(gB + 2 * R64, dB + 16384);   GLOAD(gB + 3 * R64, dB + 24576);
        gA += 64; gB += 64;
    }
    VMC0(); SBAR(); SCH0();

    const int aOff = (wr * 64 + fr) * 128;   // + (mi&3)*2048; +16384 for hi half
    const int bOff = (wc * 32 + fr) * 128;   // + (ni&1)*2048; +16384 for hi half

    bf16x8 af[4][2], bfLo[2][2], bfHi[2][2];
    int u = 0;

    // MODE: 0 = steady (stages tile u+1), 1 = last tile (no staging)
    auto tile = [&](auto mC) {
        constexpr int MODE = decltype(mC)::value;
        char* bufA = lds + (u & 1) * 32768;
        char* bufB = lds + 65536 + (u & 1) * 32768;

        // ---- upfront reads: af-lo (8) + bfLo (4) ----
        #pragma unroll
        for (int mi = 0; mi < 4; ++mi)
            #pragma unroll
            for (int ks = 0; ks < 2; ++ks)
                af[mi][ks] = *(const bf16x8*)(bufA + aOff + mi * 2048 + koff[ks]);
        #pragma unroll
        for (int ni = 0; ni < 2; ++ni)
            #pragma unroll
            for (int ks = 0; ks < 2; ++ks)
                bfLo[ni][ks] = *(const bf16x8*)(bufB + bOff + ni * 2048 + koff[ks]);

        __builtin_amdgcn_s_setprio(1);

        // ---- q00: af-lo x bfLo ----
        #pragma unroll
        for (int mi = 0; mi < 4; ++mi)
            #pragma unroll
            for (int ni = 0; ni < 2; ++ni)
                #pragma unroll
                for (int ks = 0; ks < 2; ++ks)
                    acc[mi][ni] = __builtin_amdgcn_mfma_f32_16x16x32_bf16(
                        af[mi][ks], bfLo[ni][ks], acc[mi][ni], 0, 0, 0);

        // ---- bfHi reads (4), to be interleaved into q00's issue gaps ----
        #pragma unroll
        for (int ni = 0; ni < 2; ++ni)
            #pragma unroll
            for (int ks = 0; ks < 2; ++ks)
                bfHi[ni][ks] = *(const bf16x8*)(bufB + bOff + 16384 + ni * 2048 + koff[ks]);

        // ---- q01: af-lo x bfHi ----
        #pragma unroll
        for (int mi = 0; mi < 4; ++mi)
            #pragma unroll
            for (int ni = 0; ni < 2; ++ni)
                #pragma unroll
                for (int ks = 0; ks < 2; ++ks)
                    acc[mi][2 + ni] = __builtin_amdgcn_mfma_f32_16x16x32_bf16(
                        af[mi][ks], bfHi[ni][ks], acc[mi][2 + ni], 0, 0, 0);

        // ---- af-hi reads (8, WAR-reuse of af regs) ----
        #pragma unroll
        for (int mi = 0; mi < 4; ++mi)
            #pragma unroll
            for (int ks = 0; ks < 2; ++ks)
                af[mi][ks] = *(const bf16x8*)(bufA + aOff + 16384 + mi * 2048 + koff[ks]);

        // ---- stage tile u+1 (8 gloads), interleaved into q10's gaps ----
        if constexpr (MODE == 0) {
            char* dA = lds + ((u & 1) ^ 1) * 32768 + tid * 16;
            char* dB = lds + 65536 + ((u & 1) ^ 1) * 32768 + tid * 16;
            GLOAD(gA,           dA);           GLOAD(gA + R64,     dA + 8192);
            GLOAD(gA + 2 * R64, dA + 16384);   GLOAD(gA + 3 * R64, dA + 24576);
            GLOAD(gB,           dB);           GLOAD(gB + R64,     dB + 8192);
            GLOAD(gB + 2 * R64, dB + 16384);   GLOAD(gB + 3 * R64, dB + 24576);
            gA += 64; gB += 64;
        }

        // ---- q10: af-hi x bfLo ----
        #pragma unroll
        for (int mi = 0; mi < 4; ++mi)
            #pragma unroll
            for (int ni = 0; ni < 2; ++ni)
                #pragma unroll
                for (int ks = 0; ks < 2; ++ks)
                    acc[4 + mi][ni] = __builtin_amdgcn_mfma_f32_16x16x32_bf16(
                        af[mi][ks], bfLo[ni][ks], acc[4 + mi][ni], 0, 0, 0);

        // ---- q11: af-hi x bfHi ----
        #pragma unroll
        for (int mi = 0; mi < 4; ++mi)
            #pragma unroll
            for (int ni = 0; ni < 2; ++ni)
                #pragma unroll
                for (int ks = 0; ks < 2; ++ks)
                    acc[4 + mi][2 + ni] = __builtin_amdgcn_mfma_f32_16x16x32_bf16(
                        af[mi][ks], bfHi[ni][ks], acc[4 + mi][2 + ni], 0, 0, 0);

        __builtin_amdgcn_s_setprio(0);

        // ---- T19 pin: DS12 | 12x{MFMA2,DS1} | 8x{MFMA2,VMEM1} | MFMA24 ----
        SGB(0x100, 12);
        #pragma unroll
        for (int i = 0; i < 12; ++i) { SGB(0x8, 2); SGB(0x100, 1); }
        if constexpr (MODE == 0) {
            #pragma unroll
            for (int i = 0; i < 8; ++i) { SGB(0x8, 2); SGB(0x30, 1); }
        } else {
            SGB(0x8, 16);
        }
        SGB(0x8, 24);

        if constexpr (MODE == 0) {
            VMC0();          // tile u+1 resident (issued ~2 quadrants ago)
            SBAR(); SCH0();  // all waves done reading buf(u)
        }
    };

    for (u = 0; u < NTILE - 1; ++u) tile(ModeT<0>{});
    tile(ModeT<1>{});

    // epilogue: write f32 partials (interleaved-quadrant mapping)
    float* Pp = P + (size_t)sk * rows * OUT_F;
    const size_t orow0 = (size_t)bm * 256 + (size_t)wr * 64;
    const int    ocol0 = bn * 256 + wc * 32;
    #pragma unroll
    for (int n = 0; n < 4; ++n) {
        const int col = ocol0 + (n & 1) * 16 + (n >> 1) * 128 + fr;
        #pragma unroll
        for (int m = 0; m < 8; ++m) {
            const size_t r0 = orow0 + (m & 3) * 16 + (m >> 2) * 128 + kg * 4;
            #pragma unroll
            for (int j = 0; j < 4; ++j)
                Pp[(r0 + j) * OUT_F + col] = acc[m][n][j];
        }
    }
}

// out = P0 + P1 + bias
__global__ __launch_bounds__(256)
void reduce_kan(const float* __restrict__ P, const float* __restrict__ bias,
                float* __restrict__ out, int n4, int skStride4)
{
    const float4* p0 = (const float4*)P;
    const float4* p1 = p0 + skStride4;
    const float4* bv = (const float4*)bias;
    float4* o = (float4*)out;
    for (int i = blockIdx.x * blockDim.x + threadIdx.x; i < n4;
         i += gridDim.x * blockDim.x) {
        float4 a = p0[i], b = p1[i], c = bv[i & 255];
        float4 r;
        r.x = a.x + b.x + c.x;  r.y = a.y + b.y + c.y;
        r.z = a.z + b.z + c.z;  r.w = a.w + b.w + c.w;
        o[i] = r;
    }
}

extern "C" void kernel_launch(void* const* d_in, const int* in_sizes, int n_in,
                              void* d_out, int out_size, void* d_ws, size_t ws_size,
                              hipStream_t stream)
{
    const float* x    = (const float*)d_in[0];
    const float* W    = (const float*)d_in[1];
    const float* bias = (const float*)d_in[2];
    const float* spl  = (const float*)d_in[3];
    const float* grid = (const float*)d_in[4];
    float* out = (float*)d_out;

    unsigned short* Bw = (unsigned short*)d_ws;               // 18.9 MB
    unsigned short* Aw = Bw + (size_t)OUT_F * KTOT;

    // per-row ws: A bf16 (18432 B) + 2x f32 partial (8192 B)
    const size_t bBytes = (size_t)OUT_F * KTOT * 2;
    size_t avail = ws_size > bBytes ? ws_size - bBytes : 0;
    long maxRows = (long)(avail / 26624);
    int chunk = (maxRows >= TOKENS) ? TOKENS : (int)((maxRows / 256) * 256);
    if (chunk < 256) chunk = 256;
    float* Pp = (float*)(Aw + (size_t)chunk * KTOT);

    if (chunk == TOKENS) {
        // fused prep (A + B in one BW-bound sweep), then one GEMM + reduce
        prep_fused<<<(TOKENS * IN_F) / 256 + (OUT_F * (KTOT / 8)) / 256,
                     256, 0, stream>>>(x, grid, W, spl, Aw, Bw);
        gemm_kan2<<<(TOKENS >> 8) * 8, 512, 0, stream>>>(Aw, Bw, Pp, TOKENS);
        int n4 = TOKENS * 256;
        reduce_kan<<<2048, 256, 0, stream>>>(Pp, bias, out, n4, n4);
    } else {
        prep_b_kernel<<<(OUT_F * (KTOT / 8)) / 256, 256, 0, stream>>>(W, spl, Bw);
        for (int t0 = 0; t0 < TOKENS; t0 += chunk) {
            int rows = (TOKENS - t0 < chunk) ? (TOKENS - t0) : chunk;
            prep_a_kernel<<<(rows * IN_F) / 256, 256, 0, stream>>>(
                x + (size_t)t0 * IN_F, grid, Aw);
            gemm_kan2<<<(rows >> 8) * 8, 512, 0, stream>>>(Aw, Bw, Pp, rows);
            int n4 = rows * 256;
            int rblocks = (n4 + 255) / 256; if (rblocks > 2048) rblocks = 2048;
            reduce_kan<<<rblocks, 256, 0, stream>>>(
                Pp, bias, out + (size_t)t0 * OUT_F, n4, n4);
        }
    }
}

// Round 8
// 199.071 us; speedup vs baseline: 1.0087x; 1.0087x over previous
//
#include <hip/hip_runtime.h>
#include <hip/hip_bf16.h>

#define IN_F   1024
#define OUT_F  1024
#define TOKENS 8192
#define KTOT   9216
#define KHALF  4608
#define NTILE  72          // KHALF / 64

typedef __attribute__((ext_vector_type(8))) short  bf16x8;
typedef __attribute__((ext_vector_type(4))) float  f32x4;

template<int M> struct ModeT { static constexpr int value = M; };

__device__ __forceinline__ unsigned int f2bf(float f) {
    union { float f; unsigned int u; } v; v.f = f;
    unsigned int r = v.u + 0x7fffu + ((v.u >> 16) & 1u);
    return r >> 16;
}

__device__ __forceinline__ void prep_a_body(int idx, const float* __restrict__ x,
                                            const float* __restrict__ grid,
                                            unsigned short* __restrict__ A)
{
    int t = idx >> 10;
    int i = idx & 1023;
    float xv = x[idx];
    float sil = xv / (1.0f + __expf(-xv));
    A[(size_t)t * KTOT + i] = (unsigned short)f2bf(sil);

    const float invd = 1.0f / (2.0f / 7.0f + 1e-5f);
    unsigned int h[8];
    #pragma unroll
    for (int g = 0; g < 8; ++g) {
        float d = (xv - grid[g]) * invd;
        h[g] = f2bf(__expf(-d * d));
    }
    uint4 pk;
    pk.x = h[0] | (h[1] << 16);
    pk.y = h[2] | (h[3] << 16);
    pk.z = h[4] | (h[5] << 16);
    pk.w = h[6] | (h[7] << 16);
    *reinterpret_cast<uint4*>(&A[(size_t)t * KTOT + IN_F + (size_t)i * 8]) = pk;
}

__device__ __forceinline__ void prep_b_body(int idx, const float* __restrict__ W,
                                            const float* __restrict__ spl,
                                            unsigned short* __restrict__ B)
{
    int o  = idx / (KTOT / 8);
    int c8 = idx - o * (KTOT / 8);
    const float* src = (c8 < IN_F / 8)
        ? (W   + (size_t)o * IN_F     + (size_t)c8 * 8)
        : (spl + (size_t)o * IN_F * 8 + (size_t)(c8 - IN_F / 8) * 8);
    const float4* s4 = reinterpret_cast<const float4*>(src);
    float4 lo = s4[0], hi = s4[1];
    uint4 pk;
    pk.x = f2bf(lo.x) | (f2bf(lo.y) << 16);
    pk.y = f2bf(lo.z) | (f2bf(lo.w) << 16);
    pk.z = f2bf(hi.x) | (f2bf(hi.y) << 16);
    pk.w = f2bf(hi.z) | (f2bf(hi.w) << 16);
    *reinterpret_cast<uint4*>(&B[(size_t)o * KTOT + (size_t)c8 * 8]) = pk;
}

// Fused A+B prep: blocks [0, 32768) build A (silu + basis), rest repack B.
__global__ __launch_bounds__(256)
void prep_fused(const float* __restrict__ x, const float* __restrict__ grid,
                const float* __restrict__ W, const float* __restrict__ spl,
                unsigned short* __restrict__ A, unsigned short* __restrict__ B)
{
    int b = blockIdx.x;
    if (b < (TOKENS * IN_F) / 256)
        prep_a_body(b * 256 + threadIdx.x, x, grid, A);
    else
        prep_b_body((b - (TOKENS * IN_F) / 256) * 256 + threadIdx.x, W, spl, B);
}

__global__ __launch_bounds__(256)
void prep_a_kernel(const float* __restrict__ x, const float* __restrict__ grid,
                   unsigned short* __restrict__ A)
{
    prep_a_body(blockIdx.x * blockDim.x + threadIdx.x, x, grid, A);
}

__global__ __launch_bounds__(256)
void prep_b_kernel(const float* __restrict__ W, const float* __restrict__ spl,
                   unsigned short* __restrict__ B)
{
    prep_b_body(blockIdx.x * blockDim.x + threadIdx.x, W, spl, B);
}

// ---------------------------------------------------------------------------
// 256x256 tile, BK=64, 8 waves (2M x 4N), split-K=2.
// R6 barrier-minimal body (proven 138 us): one s_barrier + one vmcnt(0) per
// K-tile, 64 MFMA between barriers, natural compiler scheduling (no SGB).
// NEW (R8): A-locality XCD remap — bid&7 == bm&7, so all 8 (bn,sk) blocks
// sharing an A-slice sit on ONE XCD; its L2 serves the 7 sibling re-reads.
//   A row(mi) = wr*64 + (mi&3)*16 + (mi>>2)*128
//   B col(ni) = wc*32 + (ni&1)*16 + (ni>>1)*128
// ---------------------------------------------------------------------------
#define GLOAD(src, dst) __builtin_amdgcn_global_load_lds( \
    (const __attribute__((address_space(1))) void*)(src),  \
    (__attribute__((address_space(3))) void*)(dst), 16, 0, 0)
#define SBAR()  __builtin_amdgcn_s_barrier()
#define SCH0()  __builtin_amdgcn_sched_barrier(0)
#define VMC0()  asm volatile("s_waitcnt vmcnt(0)" ::: "memory")

__global__ __launch_bounds__(512, 2)
void gemm_kan2(const unsigned short* __restrict__ A,
               const unsigned short* __restrict__ B,
               float* __restrict__ P, int rows)
{
    __shared__ char lds[131072];   // A dbuf [0,64K), B dbuf [64K,128K)

    const int bid  = blockIdx.x;
    // XCD remap: xcd = bid&7 (round-robin dispatch); bm ≡ xcd (mod 8) so all
    // 8 (bn,sk) siblings of one bm co-reside on one XCD and share its L2 A-slice.
    const int xcd  = bid & 7;
    const int j    = bid >> 3;
    const int sk   = j & 1;
    const int bn   = (j >> 1) & 3;
    const int bm   = (j >> 3) * 8 + xcd;
    const int tid  = threadIdx.x;
    const int wave = tid >> 6, lane = tid & 63;
    const int wr   = wave >> 2, wc = wave & 3;
    const int fr   = lane & 15, kg = lane >> 4;
    const int sw   = fr & 7;
    const int koff[2] = { (kg ^ sw) * 16, ((4 | kg) ^ sw) * 16 };
    const int k0 = sk * KHALF;

    // staging: thread covers row (tid>>3), 16B chunk (tid&7), inverse-swizzled k
    const int trow = tid >> 3;
    const int ksrc = ((tid & 7) ^ (trow & 7)) * 8;
    const unsigned short* gA = A + (size_t)(bm * 256 + trow) * KTOT + k0 + ksrc;
    const unsigned short* gB = B + (size_t)(bn * 256 + trow) * KTOT + k0 + ksrc;
    const size_t R64 = (size_t)64 * KTOT;

    f32x4 acc[8][4];
    const f32x4 zero = {0.f, 0.f, 0.f, 0.f};
    #pragma unroll
    for (int m = 0; m < 8; ++m)
        #pragma unroll
        for (int n = 0; n < 4; ++n) acc[m][n] = zero;

    // prologue: stage tile 0 -> buf0
    {
        char* dA = lds + tid * 16;
        char* dB = lds + 65536 + tid * 16;
        GLOAD(gA,           dA);           GLOAD(gA + R64,     dA + 8192);
        GLOAD(gA + 2 * R64, dA + 16384);   GLOAD(gA + 3 * R64, dA + 24576);
        GLOAD(gB,           dB);           GLOAD(gB + R64,     dB + 8192);
        GLOAD(gB + 2 * R64, dB + 16384);   GLOAD(gB + 3 * R64, dB + 24576);
        gA += 64; gB += 64;
    }
    VMC0(); SBAR(); SCH0();

    const int aOff = (wr * 64 + fr) * 128;   // + (mi&3)*2048; +16384 for hi half
    const int bOff = (wc * 32 + fr) * 128;   // + (ni&1)*2048; +16384 for hi half

    bf16x8 af[4][2], bfLo[2][2], bfHi[2][2];
    int u = 0;

    // MODE: 0 = steady (stages tile u+1), 1 = last tile (no staging)
    auto tile = [&](auto mC) {
        constexpr int MODE = decltype(mC)::value;
        char* bufA = lds + (u & 1) * 32768;
        char* bufB = lds + 65536 + (u & 1) * 32768;

        // ---- reads: af-lo, bfLo, bfHi (16 x ds_read_b128) ----
        #pragma unroll
        for (int mi = 0; mi < 4; ++mi)
            #pragma unroll
            for (int ks = 0; ks < 2; ++ks)
                af[mi][ks] = *(const bf16x8*)(bufA + aOff + mi * 2048 + koff[ks]);
        #pragma unroll
        for (int ni = 0; ni < 2; ++ni)
            #pragma unroll
            for (int ks = 0; ks < 2; ++ks) {
                bfLo[ni][ks] = *(const bf16x8*)(bufB + bOff + ni * 2048 + koff[ks]);
                bfHi[ni][ks] = *(const bf16x8*)(bufB + bOff + 16384 + ni * 2048 + koff[ks]);
            }

        // ---- stage tile u+1 into the other buffers ----
        if constexpr (MODE == 0) {
            char* dA = lds + ((u & 1) ^ 1) * 32768 + tid * 16;
            char* dB = lds + 65536 + ((u & 1) ^ 1) * 32768 + tid * 16;
            GLOAD(gA,           dA);           GLOAD(gA + R64,     dA + 8192);
            GLOAD(gA + 2 * R64, dA + 16384);   GLOAD(gA + 3 * R64, dA + 24576);
            GLOAD(gB,           dB);           GLOAD(gB + R64,     dB + 8192);
            GLOAD(gB + 2 * R64, dB + 16384);   GLOAD(gB + 3 * R64, dB + 24576);
            gA += 64; gB += 64;
        }
        SCH0();

        // ---- q00: af-lo x bfLo ----
        __builtin_amdgcn_s_setprio(1);
        #pragma unroll
        for (int mi = 0; mi < 4; ++mi)
            #pragma unroll
            for (int ni = 0; ni < 2; ++ni)
                #pragma unroll
                for (int ks = 0; ks < 2; ++ks)
                    acc[mi][ni] = __builtin_amdgcn_mfma_f32_16x16x32_bf16(
                        af[mi][ks], bfLo[ni][ks], acc[mi][ni], 0, 0, 0);
        __builtin_amdgcn_s_setprio(0);

        // ---- q01: af-lo x bfHi ----
        __builtin_amdgcn_s_setprio(1);
        #pragma unroll
        for (int mi = 0; mi < 4; ++mi)
            #pragma unroll
            for (int ni = 0; ni < 2; ++ni)
                #pragma unroll
                for (int ks = 0; ks < 2; ++ks)
                    acc[mi][2 + ni] = __builtin_amdgcn_mfma_f32_16x16x32_bf16(
                        af[mi][ks], bfHi[ni][ks], acc[mi][2 + ni], 0, 0, 0);
        __builtin_amdgcn_s_setprio(0);

        // ---- af-hi reads (8 x ds_read_b128), overlap q01 drain ----
        #pragma unroll
        for (int mi = 0; mi < 4; ++mi)
            #pragma unroll
            for (int ks = 0; ks < 2; ++ks)
                af[mi][ks] = *(const bf16x8*)(bufA + aOff + 16384 + mi * 2048 + koff[ks]);

        // ---- q10: af-hi x bfLo ----
        __builtin_amdgcn_s_setprio(1);
        #pragma unroll
        for (int mi = 0; mi < 4; ++mi)
            #pragma unroll
            for (int ni = 0; ni < 2; ++ni)
                #pragma unroll
                for (int ks = 0; ks < 2; ++ks)
                    acc[4 + mi][ni] = __builtin_amdgcn_mfma_f32_16x16x32_bf16(
                        af[mi][ks], bfLo[ni][ks], acc[4 + mi][ni], 0, 0, 0);
        __builtin_amdgcn_s_setprio(0);

        // ---- q11: af-hi x bfHi ----
        __builtin_amdgcn_s_setprio(1);
        #pragma unroll
        for (int mi = 0; mi < 4; ++mi)
            #pragma unroll
            for (int ni = 0; ni < 2; ++ni)
                #pragma unroll
                for (int ks = 0; ks < 2; ++ks)
                    acc[4 + mi][2 + ni] = __builtin_amdgcn_mfma_f32_16x16x32_bf16(
                        af[mi][ks], bfHi[ni][ks], acc[4 + mi][2 + ni], 0, 0, 0);
        __builtin_amdgcn_s_setprio(0);

        SCH0();
        if constexpr (MODE == 0) {
            VMC0();          // tile u+1 resident
            SBAR(); SCH0();  // all waves done reading buf(u); safe to overwrite next
        }
    };

    for (u = 0; u < NTILE - 1; ++u) tile(ModeT<0>{});
    tile(ModeT<1>{});

    // epilogue: write f32 partials (interleaved-quadrant mapping)
    float* Pp = P + (size_t)sk * rows * OUT_F;
    const size_t orow0 = (size_t)bm * 256 + (size_t)wr * 64;
    const int    ocol0 = bn * 256 + wc * 32;
    #pragma unroll
    for (int n = 0; n < 4; ++n) {
        const int col = ocol0 + (n & 1) * 16 + (n >> 1) * 128 + fr;
        #pragma unroll
        for (int m = 0; m < 8; ++m) {
            const size_t r0 = orow0 + (m & 3) * 16 + (m >> 2) * 128 + kg * 4;
            #pragma unroll
            for (int j2 = 0; j2 < 4; ++j2)
                Pp[(r0 + j2) * OUT_F + col] = acc[m][n][j2];
        }
    }
}

// out = P0 + P1 + bias
__global__ __launch_bounds__(256)
void reduce_kan(const float* __restrict__ P, const float* __restrict__ bias,
                float* __restrict__ out, int n4, int skStride4)
{
    const float4* p0 = (const float4*)P;
    const float4* p1 = p0 + skStride4;
    const float4* bv = (const float4*)bias;
    float4* o = (float4*)out;
    for (int i = blockIdx.x * blockDim.x + threadIdx.x; i < n4;
         i += gridDim.x * blockDim.x) {
        float4 a = p0[i], b = p1[i], c = bv[i & 255];
        float4 r;
        r.x = a.x + b.x + c.x;  r.y = a.y + b.y + c.y;
        r.z = a.z + b.z + c.z;  r.w = a.w + b.w + c.w;
        o[i] = r;
    }
}

extern "C" void kernel_launch(void* const* d_in, const int* in_sizes, int n_in,
                              void* d_out, int out_size, void* d_ws, size_t ws_size,
                              hipStream_t stream)
{
    const float* x    = (const float*)d_in[0];
    const float* W    = (const float*)d_in[1];
    const float* bias = (const float*)d_in[2];
    const float* spl  = (const float*)d_in[3];
    const float* grid = (const float*)d_in[4];
    float* out = (float*)d_out;

    unsigned short* Bw = (unsigned short*)d_ws;               // 18.9 MB
    unsigned short* Aw = Bw + (size_t)OUT_F * KTOT;

    // per-row ws: A bf16 (18432 B) + 2x f32 partial (8192 B)
    const size_t bBytes = (size_t)OUT_F * KTOT * 2;
    size_t avail = ws_size > bBytes ? ws_size - bBytes : 0;
    long maxRows = (long)(avail / 26624);
    int chunk = (maxRows >= TOKENS) ? TOKENS : (int)((maxRows / 256) * 256);
    if (chunk < 256) chunk = 256;
    float* Pp = (float*)(Aw + (size_t)chunk * KTOT);

    if (chunk == TOKENS) {
        // fused prep (A + B in one BW-bound sweep), then one GEMM + reduce
        prep_fused<<<(TOKENS * IN_F) / 256 + (OUT_F * (KTOT / 8)) / 256,
                     256, 0, stream>>>(x, grid, W, spl, Aw, Bw);
        gemm_kan2<<<(TOKENS >> 8) * 8, 512, 0, stream>>>(Aw, Bw, Pp, TOKENS);
        int n4 = TOKENS * 256;
        reduce_kan<<<2048, 256, 0, stream>>>(Pp, bias, out, n4, n4);
    } else {
        prep_b_kernel<<<(OUT_F * (KTOT / 8)) / 256, 256, 0, stream>>>(W, spl, Bw);
        for (int t0 = 0; t0 < TOKENS; t0 += chunk) {
            int rows = (TOKENS - t0 < chunk) ? (TOKENS - t0) : chunk;
            prep_a_kernel<<<(rows * IN_F) / 256, 256, 0, stream>>>(
                x + (size_t)t0 * IN_F, grid, Aw);
            gemm_kan2<<<(rows >> 8) * 8, 512, 0, stream>>>(Aw, Bw, Pp, rows);
            int n4 = rows * 256;
            int rblocks = (n4 + 255) / 256; if (rblocks > 2048) rblocks = 2048;
            reduce_kan<<<rblocks, 256, 0, stream>>>(
                Pp, bias, out + (size_t)t0 * OUT_F, n4, n4);
        }
    }
}